// Round 1
// baseline (1259.691 us; speedup 1.0000x reference)
//
#include <hip/hip_runtime.h>
#include <stdint.h>

typedef __bf16 bf16x8 __attribute__((ext_vector_type(8)));
typedef float f32x4 __attribute__((ext_vector_type(4)));

#define MFMA16(A, B, C) __builtin_amdgcn_mfma_f32_16x16x32_bf16((A), (B), (C), 0, 0, 0)

__device__ __forceinline__ float b2f(unsigned short u) {
    union { unsigned int i; float f; } v; v.i = ((unsigned int)u) << 16; return v.f;
}
__device__ __forceinline__ unsigned short f2b(float f) {
    union { float f; unsigned int i; } v; v.f = f;
    unsigned int x = v.i;
    return (unsigned short)((x + 0x7FFFu + ((x >> 16) & 1u)) >> 16);
}
__device__ __forceinline__ float ldf(const void* p, long i, int isbf) {
    return isbf ? b2f(((const unsigned short*)p)[i]) : ((const float*)p)[i];
}

// Probe storage dtype (bf16 vs f32) of float arrays, and idx width (i32 vs i64).
__global__ void k_probe(const unsigned int* __restrict__ wq,
                        const unsigned int* __restrict__ idxw, int* __restrict__ flags) {
    if (threadIdx.x == 0) {
        int ok = 0;
        for (int i = 0; i < 8; i++) {
            unsigned int e = (wq[i] >> 7) & 0xFFu;
            if (e >= 0x60u && e <= 0x7Cu) ok++;
        }
        flags[0] = (ok == 8) ? 1 : 0;
        int z = 0, lr = 0;
        for (int i = 0; i < 4; i++) {
            if (idxw[2 * i + 1] == 0u) z++;
            if (idxw[2 * i] < 0x4000000u) lr++;
        }
        flags[1] = (z == 4 && lr == 4) ? 1 : 0;
    }
}

// Q[c] = S . Wq[c,:] + bq[c]; decode prelu_a
__global__ void k_q(const void* __restrict__ S, const void* __restrict__ Wq,
                    const void* __restrict__ bq, const void* __restrict__ prelu,
                    const int* __restrict__ flags, float* __restrict__ Q,
                    float* __restrict__ pf) {
    int isbf = flags[0];
    int c = threadIdx.x;
    float acc = 0.f;
    for (int j = 0; j < 256; j++) acc += ldf(S, j, isbf) * ldf(Wq, (long)c * 256 + j, isbf);
    Q[c] = acc + ldf(bq, c, isbf);
    if (c == 0)
        pf[0] = isbf ? b2f(((const unsigned short*)prelu)[0]) : ((const float*)prelu)[0];
}

// qkb[h,j] = (Wk[h*64:,j] . Q_h)/16 (bf16; rows 4..15 zero); qb[h] = (bk_h . Q_h)/16
__global__ void k_qk(const void* __restrict__ Wk, const void* __restrict__ bk,
                     const float* __restrict__ Q, const int* __restrict__ flags,
                     unsigned short* __restrict__ qkb, float* __restrict__ qb) {
    int isbf = flags[0];
    int h = blockIdx.x, j = threadIdx.x;
    float acc = 0.f;
    if (h < 4) {
        for (int d = 0; d < 64; d++) acc += ldf(Wk, (long)(h * 64 + d) * 256 + j, isbf) * Q[h * 64 + d];
        acc *= 0.0625f;
    }
    qkb[h * 256 + j] = f2b(acc);
    if (j == 0) {
        float s = 0.f;
        if (h < 4) {
            for (int d = 0; d < 64; d++) s += ldf(bk, h * 64 + d, isbf) * Q[h * 64 + d];
            s *= 0.0625f;
        }
        qb[h] = s;
    }
}

// Convert Wv, Wo to bf16 scratch.
__global__ void k_cvt(const void* __restrict__ Wv, const void* __restrict__ Wo,
                      const int* __restrict__ flags, unsigned short* __restrict__ Wvb,
                      unsigned short* __restrict__ Wob) {
    int isbf = flags[0];
    long i = (long)blockIdx.x * 256 + threadIdx.x;
    const void* src = (i < 65536) ? Wv : Wo;
    unsigned short* dst = (i < 65536) ? Wvb : Wob;
    long k = (i < 65536) ? i : i - 65536;
    dst[k] = isbf ? ((const unsigned short*)src)[k] : f2b(((const float*)src)[k]);
}

// ---- counting sort of checkins by POI ----

__global__ void k_hist(const int* __restrict__ idxp, const int* __restrict__ flags,
                       int* __restrict__ counts, int N) {
    int is64 = flags[1];
    int i = blockIdx.x * 256 + threadIdx.x;
    if (i < N) {
        int p = is64 ? idxp[(long)i << 1] : idxp[i];
        atomicAdd(&counts[p], 1);
    }
}

// per-256-block exclusive scan; block totals to bsum
__global__ __launch_bounds__(256) void k_scan1(const int* __restrict__ counts,
                                               int* __restrict__ offs,
                                               int* __restrict__ bsum, int P) {
    __shared__ int sh[256];
    int t = threadIdx.x;
    int i = blockIdx.x * 256 + t;
    int v = (i < P) ? counts[i] : 0;
    int s = v;
    sh[t] = s;
    __syncthreads();
    for (int d = 1; d < 256; d <<= 1) {
        int add = (t >= d) ? sh[t - d] : 0;
        __syncthreads();
        s += add;
        sh[t] = s;
        __syncthreads();
    }
    if (i < P) offs[i] = s - v;
    if (t == 255) bsum[blockIdx.x] = s;
}

// in-place exclusive scan of block totals (nb values, single block)
__global__ __launch_bounds__(256) void k_scan2(int* __restrict__ bsum, int nb) {
    __shared__ int sh[256];
    int t = threadIdx.x;
    int K = (nb + 255) / 256;
    int j0 = t * K;
    int local = 0;
    for (int k = 0; k < K; k++) {
        int j = j0 + k;
        if (j < nb) local += bsum[j];
    }
    int s = local;
    sh[t] = s;
    __syncthreads();
    for (int d = 1; d < 256; d <<= 1) {
        int add = (t >= d) ? sh[t - d] : 0;
        __syncthreads();
        s += add;
        sh[t] = s;
        __syncthreads();
    }
    int run = s - local;  // exclusive prefix of this thread's chunk
    for (int k = 0; k < K; k++) {
        int j = j0 + k;
        if (j < nb) { int tmp = bsum[j]; bsum[j] = run; run += tmp; }
    }
}

__global__ void k_scan3(int* __restrict__ offs, const int* __restrict__ bsum, int P) {
    int i = blockIdx.x * 256 + threadIdx.x;
    if (i < P) offs[i] += bsum[blockIdx.x];
}

__global__ void k_scatter(const int* __restrict__ idxp, const int* __restrict__ flags,
                          const int* __restrict__ offs, int* __restrict__ cursor,
                          int* __restrict__ order, int* __restrict__ pois, int N) {
    int is64 = flags[1];
    int i = blockIdx.x * 256 + threadIdx.x;
    if (i < N) {
        int p = is64 ? idxp[(long)i << 1] : idxp[i];
        int pos = atomicAdd(&cursor[p], 1);
        int j = offs[p] + pos;
        order[j] = i;
        pois[j] = p;
    }
}

// k_v: rows processed in POI-sorted order. Stage gathered x->LDS bf16; scores MFMA
// -> e, denom (run-merged atomics); V = x@WvT via MFMA; per-lane run-merge of the
// 4 consecutive rows (MFMA C layout: q*4+r) before each vagg atomic flush.
__global__ __launch_bounds__(256) void k_v(
    const void* __restrict__ x, const int* __restrict__ order,
    const int* __restrict__ pois,
    const unsigned short* __restrict__ Wvb, const unsigned short* __restrict__ qkb,
    const float* __restrict__ qb, const int* __restrict__ flags,
    float* __restrict__ denom, float* __restrict__ vagg, int N) {
    __shared__ unsigned short xs[128 * 264];
    __shared__ float es[128][4];
    int isbf = flags[0];
    int tid = threadIdx.x;
    long base = (long)blockIdx.x * 128;

    // stage 128x256 gathered x tile as bf16 (each row is a contiguous 512B read)
#pragma unroll
    for (int ch = 0; ch < 16; ch++) {
        int i16 = tid + ch * 256;
        int row = i16 >> 5;
        int col = (i16 & 31) * 8;
        long grow = base + row;
        uint4 t;
        if (grow < N) {
            long n = (long)order[grow];
            if (isbf) {
                t = *(const uint4*)((const unsigned short*)x + n * 256 + col);
            } else {
                const float* xp = (const float*)x + n * 256 + col;
                float4 a = *(const float4*)xp;
                float4 b = *(const float4*)(xp + 4);
                t.x = (unsigned int)f2b(a.x) | ((unsigned int)f2b(a.y) << 16);
                t.y = (unsigned int)f2b(a.z) | ((unsigned int)f2b(a.w) << 16);
                t.z = (unsigned int)f2b(b.x) | ((unsigned int)f2b(b.y) << 16);
                t.w = (unsigned int)f2b(b.z) | ((unsigned int)f2b(b.w) << 16);
            }
        } else {
            t.x = t.y = t.z = t.w = 0u;
        }
        *(uint4*)&xs[row * 264 + col] = t;
    }
    __syncthreads();

    int w = tid >> 6, l = tid & 63;
    int m = l & 15, q = l >> 4;

    // POI ids for this lane's C-fragment rows (sorted order; -1 = invalid row)
    int ids[2][4];
#pragma unroll
    for (int g2 = 0; g2 < 2; g2++)
#pragma unroll
        for (int r = 0; r < 4; r++) {
            long gr = base + w * 32 + g2 * 16 + q * 4 + r;
            ids[g2][r] = (gr < N) ? pois[gr] : -1;
        }

    // A fragments (hoisted: reused for scores and all 16 V tiles)
    bf16x8 a[2][8];
#pragma unroll
    for (int g2 = 0; g2 < 2; g2++)
#pragma unroll
        for (int s = 0; s < 8; s++)
            a[g2][s] = *(const bf16x8*)&xs[(w * 32 + g2 * 16 + m) * 264 + q * 8 + s * 32];

    // scores -> e -> denom atomics (run-merged over the lane's 4 consecutive rows)
    {
        const bf16x8* qkp = (const bf16x8*)(qkb + (size_t)m * 256);
        bf16x8 qf[8];
#pragma unroll
        for (int s = 0; s < 8; s++) qf[s] = qkp[q + s * 4];
        float qbm = qb[m & 3];
#pragma unroll
        for (int g2 = 0; g2 < 2; g2++) {
            f32x4 sacc = {0.f, 0.f, 0.f, 0.f};
#pragma unroll
            for (int s = 0; s < 8; s++) sacc = MFMA16(a[g2][s], qf[s], sacc);
            if (m < 4) {
                int rid = -1;
                float run = 0.f;
#pragma unroll
                for (int r = 0; r < 4; r++) {
                    int row = w * 32 + g2 * 16 + q * 4 + r;
                    long gr = base + row;
                    float e = 0.f;
                    if (gr < N) e = __expf(sacc[r] + qbm);  // |score| << 1: shift-free safe
                    es[row][m] = e;
                    int id = ids[g2][r];
                    if (id == rid) {
                        run += e;
                    } else {
                        if (rid >= 0) unsafeAtomicAdd(&denom[(long)rid * 4 + m], run);
                        rid = id;
                        run = e;
                    }
                }
                if (rid >= 0) unsafeAtomicAdd(&denom[(long)rid * 4 + m], run);
            }
        }
    }
    // es: written and read by the same wave only -> no barrier needed

    // V tiles + e-weighted scatter with per-lane run merge (head = t>>2)
#pragma unroll 1
    for (int t = 0; t < 16; t++) {
        int h_t = t >> 2;
        const bf16x8* wvp = (const bf16x8*)(Wvb + (size_t)(t * 16 + m) * 256);
        bf16x8 b[8];
#pragma unroll
        for (int s = 0; s < 8; s++) b[s] = wvp[q + s * 4];
#pragma unroll
        for (int g2 = 0; g2 < 2; g2++) {
            f32x4 acc = {0.f, 0.f, 0.f, 0.f};
#pragma unroll
            for (int s = 0; s < 8; s++) acc = MFMA16(a[g2][s], b[s], acc);
            int rid = -1;
            float run = 0.f;
#pragma unroll
            for (int r = 0; r < 4; r++) {
                int row = w * 32 + g2 * 16 + q * 4 + r;
                float val = acc[r] * es[row][h_t];
                int id = ids[g2][r];
                if (id == rid) {
                    run += val;
                } else {
                    if (rid >= 0) unsafeAtomicAdd(&vagg[(long)rid * 256 + t * 16 + m], run);
                    rid = id;
                    run = val;
                }
            }
            if (rid >= 0) unsafeAtomicAdd(&vagg[(long)rid * 256 + t * 16 + m], run);
        }
    }
}

// k_out: O = Q + (vagg + bv*den)/(den+1e-16)  [O kept f32 in LDS];
//        out = prelu(O + relu(O@WoT + bo))
__global__ __launch_bounds__(256) void k_out(
    const float* __restrict__ Q, const float* __restrict__ denom,
    const float* __restrict__ vagg, const void* __restrict__ bv,
    const unsigned short* __restrict__ Wob, const void* __restrict__ bo,
    const float* __restrict__ pf, const int* __restrict__ flags,
    void* __restrict__ out, int P) {
    __shared__ float Os[4][16 * 264];
    int isbf = flags[0];
    int tid = threadIdx.x;
    int w = tid >> 6, l = tid & 63;
    int m = l & 15, q = l >> 4;
    long pbase = (long)blockIdx.x * 64 + w * 16;
    float aP = pf[0];
    long pm = pbase + m;
    bool vm = pm < P;

    float den4[4], rd4[4];
#pragma unroll
    for (int h = 0; h < 4; h++) {
        float d = vm ? denom[pm * 4 + h] : 0.f;
        den4[h] = d;
        rd4[h] = 1.0f / (d + 1e-16f);
    }

    bf16x8 of[8];
#pragma unroll
    for (int s = 0; s < 8; s++) {
        int c0 = q * 8 + s * 32;
        int h = s >> 1;  // head of the 8 contiguous channels c0..c0+7
        bf16x8 ov;
        if (vm) {
            const float* ag = vagg + pm * 256 + c0;
#pragma unroll
            for (int j = 0; j < 8; j++) {
                float o = Q[c0 + j] + (ag[j] + ldf(bv, c0 + j, isbf) * den4[h]) * rd4[h];
                Os[w][m * 264 + c0 + j] = o;
                ov[j] = (__bf16)o;
            }
        } else {
#pragma unroll
            for (int j = 0; j < 8; j++) { Os[w][m * 264 + c0 + j] = 0.f; ov[j] = (__bf16)0.0f; }
        }
        of[s] = ov;
    }
    // Os: same-wave write/read only -> no barrier needed

#pragma unroll 1
    for (int t = 0; t < 16; t++) {
        const bf16x8* wop = (const bf16x8*)(Wob + (size_t)(t * 16 + m) * 256);
        f32x4 acc = {0.f, 0.f, 0.f, 0.f};
#pragma unroll
        for (int s = 0; s < 8; s++) acc = MFMA16(of[s], wop[q + s * 4], acc);
        int c = t * 16 + m;
        float boc = ldf(bo, c, isbf);
#pragma unroll
        for (int r = 0; r < 4; r++) {
            int row = q * 4 + r;
            long p = pbase + row;
            if (p < P) {
                float Ov = Os[w][row * 264 + c];
                float lin = fmaxf(acc[r] + boc, 0.f);
                float res = Ov + lin;
                res = (res >= 0.f) ? res : aP * res;
                if (res != res) res = 0.f;
                if (isbf) ((unsigned short*)out)[p * 256 + c] = f2b(res);
                else      ((float*)out)[p * 256 + c] = res;
            }
        }
    }
}

extern "C" void kernel_launch(void* const* d_in, const int* in_sizes, int n_in,
                              void* d_out, int out_size, void* d_ws, size_t ws_size,
                              hipStream_t stream) {
    const void* x  = d_in[0];
    const int* idx = (const int*)d_in[1];
    const void* Wq = d_in[3];
    const void* bq = d_in[4];
    const void* Wk = d_in[5];
    const void* bk = d_in[6];
    const void* Wv = d_in[7];
    const void* bv = d_in[8];
    const void* Wo = d_in[9];
    const void* bo = d_in[10];
    const void* S  = d_in[11];
    const void* pr = d_in[12];

    int N = in_sizes[0] / 256;
    int P = out_size / 256;
    int nb1 = (P + 255) / 256;
    int nbN = (N + 255) / 256;

    float* ws = (float*)d_ws;
    int* flags          = (int*)ws;                          // 2 ints
    float* pf           = ws + 2;                            // 1
    float* Q            = ws + 16;                           // 256
    float* qb           = ws + 272;                          // 16
    unsigned short* qkb = (unsigned short*)(ws + 288);       // 16*256 bf16
    unsigned short* Wvb = (unsigned short*)(ws + 2336);      // 65536 bf16
    unsigned short* Wob = (unsigned short*)(ws + 35104);     // 65536 bf16
    float* denom        = ws + 67872;                        // P*4
    float* vagg         = denom + (size_t)P * 4;             // P*256

    // sort scratch ALIASES vagg: only used before vagg is zeroed
    int* counts = (int*)vagg;        // P
    int* cursor = counts + P;        // P
    int* offs   = cursor + P;        // P
    int* bsum   = offs + P;          // nb1

    // order/pois live past vagg (persist through k_v)
    int* order  = (int*)(vagg + (size_t)P * 256);  // N
    int* pois   = order + N;                       // N

    size_t need = (67872 + (size_t)P * 260) * sizeof(float) + (size_t)2 * N * sizeof(int);
    if (ws_size < need) return;

    hipMemsetAsync(counts, 0, (size_t)2 * P * sizeof(int), stream);

    k_probe<<<1, 64, 0, stream>>>((const unsigned int*)Wq, (const unsigned int*)idx, flags);
    k_q<<<1, 256, 0, stream>>>(S, Wq, bq, pr, flags, Q, pf);
    k_qk<<<16, 256, 0, stream>>>(Wk, bk, Q, flags, qkb, qb);
    k_cvt<<<512, 256, 0, stream>>>(Wv, Wo, flags, Wvb, Wob);

    k_hist<<<nbN, 256, 0, stream>>>(idx, flags, counts, N);
    k_scan1<<<nb1, 256, 0, stream>>>(counts, offs, bsum, P);
    k_scan2<<<1, 256, 0, stream>>>(bsum, nb1);
    k_scan3<<<nb1, 256, 0, stream>>>(offs, bsum, P);
    k_scatter<<<nbN, 256, 0, stream>>>(idx, flags, offs, cursor, order, pois, N);

    hipMemsetAsync(denom, 0, (size_t)P * 260 * sizeof(float), stream);

    k_v<<<(N + 127) / 128, 256, 0, stream>>>(x, order, pois, Wvb, qkb, qb, flags, denom, vagg, N);
    k_out<<<(P + 63) / 64, 256, 0, stream>>>(Q, denom, vagg, bv, Wob, bo, pf, flags, d_out, P);
}

// Round 2
// 1132.796 us; speedup vs baseline: 1.1120x; 1.1120x over previous
//
#include <hip/hip_runtime.h>
#include <stdint.h>

typedef __bf16 bf16x8 __attribute__((ext_vector_type(8)));
typedef float f32x4 __attribute__((ext_vector_type(4)));

#define MFMA16(A, B, C) __builtin_amdgcn_mfma_f32_16x16x32_bf16((A), (B), (C), 0, 0, 0)

__device__ __forceinline__ float b2f(unsigned short u) {
    union { unsigned int i; float f; } v; v.i = ((unsigned int)u) << 16; return v.f;
}
__device__ __forceinline__ unsigned short f2b(float f) {
    union { float f; unsigned int i; } v; v.f = f;
    unsigned int x = v.i;
    return (unsigned short)((x + 0x7FFFu + ((x >> 16) & 1u)) >> 16);
}
__device__ __forceinline__ float ldf(const void* p, long i, int isbf) {
    return isbf ? b2f(((const unsigned short*)p)[i]) : ((const float*)p)[i];
}

// Probe storage dtype (bf16 vs f32) of float arrays, and idx width (i32 vs i64).
__global__ void k_probe(const unsigned int* __restrict__ wq,
                        const unsigned int* __restrict__ idxw, int* __restrict__ flags) {
    if (threadIdx.x == 0) {
        int ok = 0;
        for (int i = 0; i < 8; i++) {
            unsigned int e = (wq[i] >> 7) & 0xFFu;
            if (e >= 0x60u && e <= 0x7Cu) ok++;
        }
        flags[0] = (ok == 8) ? 1 : 0;
        int z = 0, lr = 0;
        for (int i = 0; i < 4; i++) {
            if (idxw[2 * i + 1] == 0u) z++;
            if (idxw[2 * i] < 0x4000000u) lr++;
        }
        flags[1] = (z == 4 && lr == 4) ? 1 : 0;
    }
}

// Fused: Q[c] = S.Wq[c,:]+bq (blocks 0..3 compute their 64 rows in parallel),
// then qkb[h,j] = (Wk[h*64:,j] . Q_h)/16, qb[h] = (bk_h . Q_h)/16; decode prelu.
__global__ __launch_bounds__(256) void k_qk(
    const void* __restrict__ S, const void* __restrict__ Wq, const void* __restrict__ bq,
    const void* __restrict__ Wk, const void* __restrict__ bk, const void* __restrict__ prelu,
    const int* __restrict__ flags, float* __restrict__ Q,
    unsigned short* __restrict__ qkb, float* __restrict__ qb, float* __restrict__ pf) {
    __shared__ float Qh[64];
    __shared__ float part[256];
    int isbf = flags[0];
    int h = blockIdx.x, tid = threadIdx.x;
    if (h < 4) {
        int d = tid >> 2, quad = tid & 3;
        float ps = 0.f;
        for (int j = 0; j < 64; j++)
            ps += ldf(S, quad * 64 + j, isbf) *
                  ldf(Wq, (long)(h * 64 + d) * 256 + quad * 64 + j, isbf);
        part[tid] = ps;
        __syncthreads();
        if (quad == 0) {
            float qv = part[tid] + part[tid + 1] + part[tid + 2] + part[tid + 3] +
                       ldf(bq, h * 64 + d, isbf);
            Qh[d] = qv;
            Q[h * 64 + d] = qv;
        }
        __syncthreads();
    }
    int j = tid;
    float acc = 0.f;
    if (h < 4) {
        for (int d = 0; d < 64; d++) acc += ldf(Wk, (long)(h * 64 + d) * 256 + j, isbf) * Qh[d];
        acc *= 0.0625f;
    }
    qkb[h * 256 + j] = f2b(acc);
    if (j == 0) {
        float s = 0.f;
        if (h < 4) {
            for (int d = 0; d < 64; d++) s += ldf(bk, h * 64 + d, isbf) * Qh[d];
            s *= 0.0625f;
        }
        qb[h] = s;
    }
    if (h == 0 && j == 0)
        pf[0] = isbf ? b2f(((const unsigned short*)prelu)[0]) : ((const float*)prelu)[0];
}

// Convert Wv, Wo to bf16 scratch.
__global__ void k_cvt(const void* __restrict__ Wv, const void* __restrict__ Wo,
                      const int* __restrict__ flags, unsigned short* __restrict__ Wvb,
                      unsigned short* __restrict__ Wob) {
    int isbf = flags[0];
    long i = (long)blockIdx.x * 256 + threadIdx.x;
    const void* src = (i < 65536) ? Wv : Wo;
    unsigned short* dst = (i < 65536) ? Wvb : Wob;
    long k = (i < 65536) ? i : i - 65536;
    dst[k] = isbf ? ((const unsigned short*)src)[k] : f2b(((const float*)src)[k]);
}

// ---- counting sort of checkins by POI ----

__global__ void k_hist(const int* __restrict__ idxp, const int* __restrict__ flags,
                       int* __restrict__ counts, int N) {
    int is64 = flags[1];
    int i = blockIdx.x * 256 + threadIdx.x;
    if (i < N) {
        int p = is64 ? idxp[(long)i << 1] : idxp[i];
        atomicAdd(&counts[p], 1);
    }
}

__global__ __launch_bounds__(256) void k_scan1(const int* __restrict__ counts,
                                               int* __restrict__ offs,
                                               int* __restrict__ bsum, int P) {
    __shared__ int sh[256];
    int t = threadIdx.x;
    int i = blockIdx.x * 256 + t;
    int v = (i < P) ? counts[i] : 0;
    int s = v;
    sh[t] = s;
    __syncthreads();
    for (int d = 1; d < 256; d <<= 1) {
        int add = (t >= d) ? sh[t - d] : 0;
        __syncthreads();
        s += add;
        sh[t] = s;
        __syncthreads();
    }
    if (i < P) offs[i] = s - v;
    if (t == 255) bsum[blockIdx.x] = s;
}

__global__ __launch_bounds__(256) void k_scan2(int* __restrict__ bsum, int nb) {
    __shared__ int sh[256];
    int t = threadIdx.x;
    int K = (nb + 255) / 256;
    int j0 = t * K;
    int local = 0;
    for (int k = 0; k < K; k++) {
        int j = j0 + k;
        if (j < nb) local += bsum[j];
    }
    int s = local;
    sh[t] = s;
    __syncthreads();
    for (int d = 1; d < 256; d <<= 1) {
        int add = (t >= d) ? sh[t - d] : 0;
        __syncthreads();
        s += add;
        sh[t] = s;
        __syncthreads();
    }
    int run = s - local;
    for (int k = 0; k < K; k++) {
        int j = j0 + k;
        if (j < nb) { int tmp = bsum[j]; bsum[j] = run; run += tmp; }
    }
}

__global__ void k_scan3(int* __restrict__ offs, const int* __restrict__ bsum, int P) {
    int i = blockIdx.x * 256 + threadIdx.x;
    if (i < P) offs[i] += bsum[blockIdx.x];
}

__global__ void k_scatter(const int* __restrict__ idxp, const int* __restrict__ flags,
                          const int* __restrict__ offs, int* __restrict__ cursor,
                          int2* __restrict__ op, int N) {
    int is64 = flags[1];
    int i = blockIdx.x * 256 + threadIdx.x;
    if (i < N) {
        int p = is64 ? idxp[(long)i << 1] : idxp[i];
        int pos = atomicAdd(&cursor[p], 1);
        op[offs[p] + pos] = make_int2(i, p);
    }
}

// k_v: rows in POI-sorted order. Direct per-lane A-fragment gather (no xs LDS).
// Block-level segmented reduction in LDS: per 128-row block, build the segment
// table (<=128 contiguous POI runs), then denom and each of the 16 V-channel
// tiles are reduced per-segment and written with PLAIN STORES for interior
// POIs; atomics only for the (<=2) boundary POIs shared with neighbor blocks.
__global__ __launch_bounds__(256) void k_v(
    const void* __restrict__ x, const int2* __restrict__ op,
    const unsigned short* __restrict__ Wvb, const unsigned short* __restrict__ qkb,
    const float* __restrict__ qb, const int* __restrict__ flags,
    float* __restrict__ denom, float* __restrict__ vagg, int N) {
    __shared__ float vt[2][128][17];
    __shared__ float es[128][4];
    __shared__ int prow[128];
    __shared__ int segstart[129];
    __shared__ int segpoi[128];
    __shared__ int wtot[4];
    __shared__ int sm[4];
    int isbf = flags[0];
    int tid = threadIdx.x;
    long base = (long)blockIdx.x * 128;
    long rem = (long)N - base;
    int nv = (rem < 128) ? (int)rem : 128;

    // segment table from sorted POI ids
    if (tid < 128) prow[tid] = (tid < nv) ? op[base + tid].y : -1;
    __syncthreads();
    bool bnd = (tid < 128) && (tid < nv) && (tid == 0 || prow[tid] != prow[tid - 1]);
    unsigned long long mask = __ballot(bnd);
    if ((tid & 63) == 0) wtot[tid >> 6] = __popcll(mask);
    __syncthreads();
    int ns = wtot[0] + wtot[1];
    if (bnd) {
        int s = __popcll(mask & ((1ull << (tid & 63)) - 1)) + ((tid >= 64) ? wtot[0] : 0);
        segstart[s] = tid;
        segpoi[s] = prow[tid];
    }
    if (tid == 0) {
        segstart[ns] = nv;
        int pv = 0, nx = 0;
        if (base > 0 && op[base - 1].y == prow[0]) pv = 1;
        if (base + nv < (long)N && op[base + nv].y == prow[nv - 1]) nx = 1;
        sm[1] = pv;
        sm[2] = nx;
    }

    int w = tid >> 6, l = tid & 63;
    int m = l & 15, q = l >> 4;

    // direct global A-fragment gather (row = w*32+g2*16+m, cols q*8+s*32)
    bf16x8 a[2][8];
#pragma unroll
    for (int g2 = 0; g2 < 2; g2++) {
        long gr = base + w * 32 + g2 * 16 + m;
        long n = (gr < N) ? (long)op[gr].x : 0;
        if (isbf) {
            const unsigned short* xb = (const unsigned short*)x + n * 256 + q * 8;
#pragma unroll
            for (int s = 0; s < 8; s++) a[g2][s] = *(const bf16x8*)(xb + s * 32);
        } else {
            const float* xf = (const float*)x + n * 256 + q * 8;
#pragma unroll
            for (int s = 0; s < 8; s++) {
                float4 lo = *(const float4*)(xf + s * 32);
                float4 hi = *(const float4*)(xf + s * 32 + 4);
                bf16x8 t;
                t[0] = (__bf16)lo.x; t[1] = (__bf16)lo.y; t[2] = (__bf16)lo.z; t[3] = (__bf16)lo.w;
                t[4] = (__bf16)hi.x; t[5] = (__bf16)hi.y; t[6] = (__bf16)hi.z; t[7] = (__bf16)hi.w;
                a[g2][s] = t;
            }
        }
    }

    // scores -> e (es[row][head])
    {
        const bf16x8* qkp = (const bf16x8*)(qkb + (size_t)m * 256);
        bf16x8 qf[8];
#pragma unroll
        for (int s = 0; s < 8; s++) qf[s] = qkp[q + s * 4];
        float qbm = qb[m & 3];
#pragma unroll
        for (int g2 = 0; g2 < 2; g2++) {
            f32x4 sacc = {0.f, 0.f, 0.f, 0.f};
#pragma unroll
            for (int s = 0; s < 8; s++) sacc = MFMA16(a[g2][s], qf[s], sacc);
            if (m < 4) {
#pragma unroll
                for (int r = 0; r < 4; r++) {
                    int row = w * 32 + g2 * 16 + q * 4 + r;
                    long gr = base + row;
                    float e = 0.f;
                    if (gr < N) e = __expf(sacc[r] + qbm);  // |score| << 1: shift-free safe
                    es[row][m] = e;
                }
            }
        }
    }
    __syncthreads();  // es + segment table visible block-wide

    int pv = sm[1], nx = sm[2];

    // denom: per-segment sums (thread = (head c, seg s0); 64 segs/round)
    {
        int c = tid & 3, s0 = tid >> 2;
        for (int s = s0; s < ns; s += 64) {
            int r0 = segstart[s], r1 = segstart[s + 1];
            float sum = 0.f;
            for (int r = r0; r < r1; r++) sum += es[r][c];
            float* dst = &denom[(long)segpoi[s] * 4 + c];
            if ((s == 0 && pv) || (s == ns - 1 && nx)) unsafeAtomicAdd(dst, sum);
            else *dst = sum;
        }
    }

    // V tiles: MFMA -> e-weighted vt in LDS -> per-segment reduce -> store/atomic
#pragma unroll 1
    for (int t = 0; t < 16; t++) {
        int h_t = t >> 2;
        int buf = t & 1;
        const bf16x8* wvp = (const bf16x8*)(Wvb + (size_t)(t * 16 + m) * 256);
        bf16x8 b[8];
#pragma unroll
        for (int s = 0; s < 8; s++) b[s] = wvp[q + s * 4];
#pragma unroll
        for (int g2 = 0; g2 < 2; g2++) {
            f32x4 acc = {0.f, 0.f, 0.f, 0.f};
#pragma unroll
            for (int s = 0; s < 8; s++) acc = MFMA16(a[g2][s], b[s], acc);
#pragma unroll
            for (int r = 0; r < 4; r++) {
                int row = w * 32 + g2 * 16 + q * 4 + r;
                vt[buf][row][m] = acc[r] * es[row][h_t];
            }
        }
        __syncthreads();  // vt[buf] complete; double-buffer allows next t's writes
        {
            int c = tid & 15, s0 = tid >> 4;
            for (int s = s0; s < ns; s += 16) {
                int r0 = segstart[s], r1 = segstart[s + 1];
                float sum = 0.f;
                for (int r = r0; r < r1; r++) sum += vt[buf][r][c];
                float* dst = &vagg[(long)segpoi[s] * 256 + t * 16 + c];
                if ((s == 0 && pv) || (s == ns - 1 && nx)) unsafeAtomicAdd(dst, sum);
                else *dst = sum;
            }
        }
    }
}

// k_out: O = Q + (vagg + bv*den)/(den+1e-16)  [O kept f32 in LDS];
//        out = prelu(O + relu(O@WoT + bo))
__global__ __launch_bounds__(256) void k_out(
    const float* __restrict__ Q, const float* __restrict__ denom,
    const float* __restrict__ vagg, const void* __restrict__ bv,
    const unsigned short* __restrict__ Wob, const void* __restrict__ bo,
    const float* __restrict__ pf, const int* __restrict__ flags,
    void* __restrict__ out, int P) {
    __shared__ float Os[4][16 * 264];
    int isbf = flags[0];
    int tid = threadIdx.x;
    int w = tid >> 6, l = tid & 63;
    int m = l & 15, q = l >> 4;
    long pbase = (long)blockIdx.x * 64 + w * 16;
    float aP = pf[0];
    long pm = pbase + m;
    bool vm = pm < P;

    float den4[4], rd4[4];
#pragma unroll
    for (int h = 0; h < 4; h++) {
        float d = vm ? denom[pm * 4 + h] : 0.f;
        den4[h] = d;
        rd4[h] = 1.0f / (d + 1e-16f);
    }

    bf16x8 of[8];
#pragma unroll
    for (int s = 0; s < 8; s++) {
        int c0 = q * 8 + s * 32;
        int h = s >> 1;
        bf16x8 ov;
        if (vm) {
            const float* ag = vagg + pm * 256 + c0;
#pragma unroll
            for (int j = 0; j < 8; j++) {
                float o = Q[c0 + j] + (ag[j] + ldf(bv, c0 + j, isbf) * den4[h]) * rd4[h];
                Os[w][m * 264 + c0 + j] = o;
                ov[j] = (__bf16)o;
            }
        } else {
#pragma unroll
            for (int j = 0; j < 8; j++) { Os[w][m * 264 + c0 + j] = 0.f; ov[j] = (__bf16)0.0f; }
        }
        of[s] = ov;
    }
    // Os: same-wave write/read only -> no barrier needed

#pragma unroll 1
    for (int t = 0; t < 16; t++) {
        const bf16x8* wop = (const bf16x8*)(Wob + (size_t)(t * 16 + m) * 256);
        f32x4 acc = {0.f, 0.f, 0.f, 0.f};
#pragma unroll
        for (int s = 0; s < 8; s++) acc = MFMA16(of[s], wop[q + s * 4], acc);
        int c = t * 16 + m;
        float boc = ldf(bo, c, isbf);
#pragma unroll
        for (int r = 0; r < 4; r++) {
            int row = q * 4 + r;
            long p = pbase + row;
            if (p < P) {
                float Ov = Os[w][row * 264 + c];
                float lin = fmaxf(acc[r] + boc, 0.f);
                float res = Ov + lin;
                res = (res >= 0.f) ? res : aP * res;
                if (res != res) res = 0.f;
                if (isbf) ((unsigned short*)out)[p * 256 + c] = f2b(res);
                else      ((float*)out)[p * 256 + c] = res;
            }
        }
    }
}

extern "C" void kernel_launch(void* const* d_in, const int* in_sizes, int n_in,
                              void* d_out, int out_size, void* d_ws, size_t ws_size,
                              hipStream_t stream) {
    const void* x  = d_in[0];
    const int* idx = (const int*)d_in[1];
    const void* Wq = d_in[3];
    const void* bq = d_in[4];
    const void* Wk = d_in[5];
    const void* bk = d_in[6];
    const void* Wv = d_in[7];
    const void* bv = d_in[8];
    const void* Wo = d_in[9];
    const void* bo = d_in[10];
    const void* S  = d_in[11];
    const void* pr = d_in[12];

    int N = in_sizes[0] / 256;
    int P = out_size / 256;
    int nb1 = (P + 255) / 256;
    int nbN = (N + 255) / 256;

    float* ws = (float*)d_ws;
    int* flags          = (int*)ws;                          // 2 ints
    float* pf           = ws + 2;                            // 1
    float* Q            = ws + 16;                           // 256
    float* qb           = ws + 272;                          // 16
    unsigned short* qkb = (unsigned short*)(ws + 288);       // 16*256 bf16
    unsigned short* Wvb = (unsigned short*)(ws + 2336);      // 65536 bf16
    unsigned short* Wob = (unsigned short*)(ws + 35104);     // 65536 bf16
    float* denom        = ws + 67872;                        // P*4
    float* vagg         = denom + (size_t)P * 4;             // P*256

    // sort scratch ALIASES vagg: only used before vagg is zeroed
    int* counts = (int*)vagg;        // P
    int* cursor = counts + P;        // P
    int* offs   = cursor + P;        // P
    int* bsum   = offs + P;          // nb1

    // (order,poi) pairs live past vagg (persist through k_v)
    int2* op = (int2*)(vagg + (size_t)P * 256);  // N pairs

    size_t need = (67872 + (size_t)P * 260) * sizeof(float) + (size_t)2 * N * sizeof(int);
    if (ws_size < need) return;

    hipMemsetAsync(counts, 0, (size_t)2 * P * sizeof(int), stream);

    k_probe<<<1, 64, 0, stream>>>((const unsigned int*)Wq, (const unsigned int*)idx, flags);
    k_qk<<<16, 256, 0, stream>>>(S, Wq, bq, Wk, bk, pr, flags, Q, qkb, qb, pf);
    k_cvt<<<512, 256, 0, stream>>>(Wv, Wo, flags, Wvb, Wob);

    k_hist<<<nbN, 256, 0, stream>>>(idx, flags, counts, N);
    k_scan1<<<nb1, 256, 0, stream>>>(counts, offs, bsum, P);
    k_scan2<<<1, 256, 0, stream>>>(bsum, nb1);
    k_scan3<<<nb1, 256, 0, stream>>>(offs, bsum, P);
    k_scatter<<<nbN, 256, 0, stream>>>(idx, flags, offs, cursor, op, N);

    hipMemsetAsync(denom, 0, (size_t)P * 260 * sizeof(float), stream);

    k_v<<<(N + 127) / 128, 256, 0, stream>>>(x, op, Wvb, qkb, qb, flags, denom, vagg, N);
    k_out<<<(P + 63) / 64, 256, 0, stream>>>(Q, denom, vagg, bv, Wob, bo, pf, flags, d_out, P);
}